// Round 6
// baseline (879.017 us; speedup 1.0000x reference)
//
#include <hip/hip_runtime.h>

// SGC layer: N=100000 nodes, E=1600000 edges, D_IN=32, D_OUT=64, 2 hops,
// per-hop cut of the 160000 lowest-cosine edges (exact top-k w/ index ties).

constexpr int NN   = 100000;
constexpr int NE   = 1600000;
constexpr int DI   = 32;
constexpr int DO   = 64;
constexpr int KCUT = 160000;
constexpr int NB   = 98;      // buckets of 1024 node-ids (ceil(100000/1024))
constexpr int CH   = 4096;    // edges per bin chunk

typedef unsigned long long u64;

// ---------------- utility ----------------

__global__ void k_zero_u32(unsigned* p, int n) {
  int i = blockIdx.x * blockDim.x + threadIdx.x;
  if (i < n) p[i] = 0u;
}

__global__ void k_norm(const unsigned* __restrict__ degi, float* __restrict__ nrm) {
  int i = blockIdx.x * blockDim.x + threadIdx.x;
  if (i < NN) {
    unsigned d = degi[i]; if (d < 1u) d = 1u;
    nrm[i] = (float)(1.0 / sqrt((double)d));   // == pow(deg, -0.5)
  }
}

// ---------------- binned CSR build ----------------
// packed edge: bits 38-47 dloc (dst & 1023), 21-37 src, 0-20 eid

__global__ void k_bhist(const int* __restrict__ dst, unsigned* __restrict__ bhist) {
  __shared__ unsigned lh[128];
  int t = threadIdx.x;
  if (t < 128) lh[t] = 0u;
  __syncthreads();
  int stride = gridDim.x * blockDim.x;
  for (int e = blockIdx.x * blockDim.x + t; e < NE; e += stride)
    atomicAdd(&lh[((unsigned)dst[e]) >> 10], 1u);
  __syncthreads();
  if (t < 128 && lh[t]) atomicAdd(&bhist[t], lh[t]);
}

__global__ void k_bscan(const unsigned* __restrict__ bhist, unsigned* __restrict__ bstart,
                        unsigned* __restrict__ bcur) {
  if (threadIdx.x == 0 && blockIdx.x == 0) {
    unsigned run = 0;
    for (int b = 0; b < NB; b++) { bstart[b] = run; bcur[b] = run; run += bhist[b]; }
    bstart[NB] = run;   // == NE
  }
}

// block-aggregated multisplit: one global atomic per (bucket, chunk)
__global__ void k_bin(const int* __restrict__ src, const int* __restrict__ dst,
                      unsigned* __restrict__ bcur, u64* __restrict__ binned) {
  __shared__ unsigned h1[128], h2[128], res[128];
  int t = threadIdx.x;
  for (int base = blockIdx.x * CH; base < NE; base += gridDim.x * CH) {
    int nE = min(CH, NE - base);
    if (t < 128) h1[t] = 0u;
    __syncthreads();
    for (int i = t; i < nE; i += 256)
      atomicAdd(&h1[((unsigned)dst[base + i]) >> 10], 1u);
    __syncthreads();
    if (t < 128) { unsigned c = h1[t]; res[t] = c ? atomicAdd(&bcur[t], c) : 0u; h2[t] = 0u; }
    __syncthreads();
    for (int i = t; i < nE; i += 256) {   // chunk re-read hits L1/L2
      unsigned d = (unsigned)dst[base + i];
      unsigned bb = d >> 10;
      u64 pk = ((u64)(d & 1023u) << 38) | ((u64)(unsigned)src[base + i] << 21)
             | (u64)(unsigned)(base + i);
      unsigned r = atomicAdd(&h2[bb], 1u);
      binned[res[bb] + r] = pk;
    }
    __syncthreads();
  }
}

// per-bucket degree count in LDS -> coalesced degi write
__global__ void k_bucket_deg(const u64* __restrict__ binned, const unsigned* __restrict__ bstart,
                             unsigned* __restrict__ degi) {
  __shared__ unsigned cnt[1024];
  int t = threadIdx.x;
  int b = blockIdx.x;
  for (int i = t; i < 1024; i += 256) cnt[i] = 0u;
  __syncthreads();
  unsigned j0 = bstart[b], j1 = bstart[b + 1];
  for (unsigned j = j0 + t; j < j1; j += 256)
    atomicAdd(&cnt[(unsigned)(binned[j] >> 38)], 1u);
  __syncthreads();
  int base = b << 10;
  for (int i = t; i < 1024; i += 256)
    if (base + i < NN) degi[base + i] = cnt[i];
}

// per-bucket scatter: fill atomics hit a 4KB region, csr writes ~130KB (L2-hot)
__global__ void k_bucket_scatter(const u64* __restrict__ binned, const unsigned* __restrict__ bstart,
                                 unsigned* __restrict__ fill, uint2* __restrict__ csr) {
  int t = threadIdx.x;
  int b = blockIdx.x;
  unsigned j0 = bstart[b], j1 = bstart[b + 1];
  int base = b << 10;
  for (unsigned j = j0 + t; j < j1; j += 256) {
    u64 pk = binned[j];
    unsigned dloc = (unsigned)(pk >> 38);
    unsigned s = (unsigned)((pk >> 21) & 0x1FFFFu);
    unsigned e = (unsigned)(pk & 0x1FFFFFu);
    unsigned g = atomicAdd(&fill[base + dloc], 1u);
    csr[g] = make_uint2(s, e);
  }
}

// ---------------- prefix sum (rowptr) ----------------

__global__ void k_psum_a(const unsigned* __restrict__ degi, unsigned* __restrict__ bsum) {
  __shared__ unsigned s[1024];
  int t = threadIdx.x;
  int i = blockIdx.x * 1024 + t;
  s[t] = (i < NN) ? degi[i] : 0u;
  __syncthreads();
  for (int off = 512; off > 0; off >>= 1) {
    if (t < off) s[t] += s[t + off];
    __syncthreads();
  }
  if (t == 0) bsum[blockIdx.x] = s[0];
}

__global__ void k_psum_b(unsigned* bsum, int nb, unsigned* rowptr) {
  if (threadIdx.x == 0 && blockIdx.x == 0) {
    unsigned run = 0;
    for (int b = 0; b < nb; b++) { unsigned v = bsum[b]; bsum[b] = run; run += v; }
    rowptr[NN] = run;   // == NE
  }
}

__global__ void k_psum_c(const unsigned* __restrict__ degi, const unsigned* __restrict__ bsum,
                         unsigned* __restrict__ rowptr, unsigned* __restrict__ fill) {
  __shared__ unsigned s[1024];
  int t = threadIdx.x;
  int i = blockIdx.x * 1024 + t;
  unsigned v = (i < NN) ? degi[i] : 0u;
  s[t] = v; __syncthreads();
  for (int off = 1; off < 1024; off <<= 1) {
    unsigned x = (t >= off) ? s[t - off] : 0u;
    __syncthreads();
    s[t] += x;
    __syncthreads();
  }
  if (i < NN) {
    unsigned excl = bsum[blockIdx.x] + s[t] - v;
    rowptr[i] = excl;
    fill[i]   = excl;
  }
}

// ---------------- per-hop kernels ----------------

// 8 nodes per 256-thread block; lane = feature dim
__global__ void k_rownorm(const float* __restrict__ h, const float* __restrict__ nrm,
                          float* __restrict__ nh, float* __restrict__ hn) {
  int lane = threadIdx.x & 31;
  int n = blockIdx.x * 8 + (threadIdx.x >> 5);
  float v = h[n * DI + lane];
  double sq = (double)v * (double)v;
  #pragma unroll
  for (int m = 16; m > 0; m >>= 1) sq += __shfl_xor(sq, m, 32);
  double den = sqrt(sq);
  if (den < 1e-12) den = 1e-12;
  nh[n * DI + lane] = (float)((double)v / den);
  hn[n * DI + lane] = v * nrm[n];
}

// cosine, MLP-restructured: 32-lane group per node = 8 edge slots x 4 dim
// slices. 16 independent float4 gathers in flight per group (was 1).
// Also builds the first 12-bit radix histogram (saves a full key pass).
__global__ void k_cos(const unsigned* __restrict__ rowptr, const uint2* __restrict__ csr,
                      const float* __restrict__ nh, u64* __restrict__ key,
                      unsigned* __restrict__ hist) {
  __shared__ unsigned lh[4096];
  int t = threadIdx.x;
  for (int i = t; i < 4096; i += 256) lh[i] = 0u;
  __syncthreads();
  int lane = t & 31;
  int sl = lane >> 2;        // edge slot 0..7
  int ds = lane & 3;         // dim slice 0..3 (8 dims each)
  int n = blockIdx.x * 8 + (t >> 5);
  const float4* drow = (const float4*)(nh + (size_t)n * DI + ds * 8);
  float4 d0 = drow[0], d1 = drow[1];
  unsigned j0 = rowptr[n], j1 = rowptr[n + 1];
  for (unsigned base = j0; base < j1; base += 8) {
    unsigned j = base + sl;
    bool val = (j < j1);
    uint2 c = val ? csr[j] : make_uint2(0u, 0u);
    const float4* arow = (const float4*)(nh + (size_t)c.x * DI + ds * 8);
    float4 a0 = arow[0], a1 = arow[1];   // two independent gathers
    double p = (double)a0.x * d0.x + (double)a0.y * d0.y
             + (double)a0.z * d0.z + (double)a0.w * d0.w
             + (double)a1.x * d1.x + (double)a1.y * d1.y
             + (double)a1.z * d1.z + (double)a1.w * d1.w;
    p += __shfl_xor(p, 1, 32);
    p += __shfl_xor(p, 2, 32);
    if (val && ds == 0) {
      float cf = (float)p;
      unsigned u = __float_as_uint(cf);
      u = (u & 0x80000000u) ? ~u : (u | 0x80000000u);   // monotone float->uint
      u64 kv = ((u64)u << 32) | (u64)c.y;
      key[j] = kv;
      atomicAdd(&lh[(unsigned)(kv >> 52)], 1u);
    }
  }
  __syncthreads();
  for (int i = t; i < 4096; i += 256) if (lh[i]) atomicAdd(&hist[i], lh[i]);
}

// ---------------- radix select (K-th smallest 64-bit key) ----------------

__global__ void k_radix_init(unsigned* hist, u64* state, unsigned* cur) {
  int t = threadIdx.x;
  for (int i = t; i < 4096; i += 256) hist[i] = 0u;
  if (t == 0) { state[0] = 0ull; state[1] = (u64)KCUT; cur[0] = 0u; cur[1] = 0u; }
}

__global__ void k_hist(const u64* __restrict__ keys, const unsigned* __restrict__ cntp,
                       int n_fixed, const u64* __restrict__ state,
                       unsigned* __restrict__ hist, int shift, int check) {
  __shared__ unsigned lh[4096];
  int t = threadIdx.x;
  for (int i = t; i < 4096; i += 256) lh[i] = 0u;
  __syncthreads();
  int n = cntp ? (int)*cntp : n_fixed;
  u64 pref = state[0];
  int stride = gridDim.x * blockDim.x;
  for (int j = blockIdx.x * blockDim.x + t; j < n; j += stride) {
    u64 k = keys[j];
    bool ok = (check == 0) || (((k ^ pref) >> check) == 0ull);
    if (ok) atomicAdd(&lh[(unsigned)((k >> shift) & 4095ull)], 1u);
  }
  __syncthreads();
  for (int i = t; i < 4096; i += 256) if (lh[i]) atomicAdd(&hist[i], lh[i]);
}

__global__ void k_select(unsigned* hist, u64* state, int shift) {
  __shared__ unsigned ssum[256];
  int t = threadIdx.x;
  unsigned loc[16]; unsigned tot = 0;
  #pragma unroll
  for (int i = 0; i < 16; i++) { loc[i] = hist[t * 16 + i]; tot += loc[i]; }
  #pragma unroll
  for (int i = 0; i < 16; i++) hist[t * 16 + i] = 0u;
  unsigned krem = (unsigned)state[1];
  ssum[t] = tot; __syncthreads();
  for (int off = 1; off < 256; off <<= 1) {
    unsigned x = (t >= off) ? ssum[t - off] : 0u;
    __syncthreads();
    ssum[t] += x;
    __syncthreads();
  }
  unsigned incl = ssum[t], excl = incl - tot;
  if (incl >= krem && excl < krem) {
    unsigned run = excl; int b = 0; unsigned nk = 0;
    #pragma unroll
    for (int i = 0; i < 16; i++) {
      if (krem <= run + loc[i]) { b = t * 16 + i; nk = krem - run; break; }
      run += loc[i];
    }
    state[0] |= ((u64)b) << shift;
    state[1] = (u64)nk;
  }
}

// block-aggregated compaction: LDS staging + one global atomic per flush
__global__ void k_compact(const u64* __restrict__ keys, const unsigned* __restrict__ cntp,
                          int n_fixed, const u64* __restrict__ state, int check,
                          u64* __restrict__ outbuf, unsigned* __restrict__ cursor) {
  __shared__ u64 buf[768];
  __shared__ unsigned cnt, gbase;
  int t = threadIdx.x;
  if (t == 0) cnt = 0u;
  __syncthreads();
  int n = cntp ? (int)*cntp : n_fixed;
  u64 pref = state[0];
  int stride = gridDim.x * blockDim.x;
  for (int j0 = blockIdx.x * blockDim.x; j0 < n; j0 += stride) {
    int j = j0 + t;
    if (j < n) {
      u64 k = keys[j];
      if (((k ^ pref) >> check) == 0ull) {
        unsigned pos = atomicAdd(&cnt, 1u);
        buf[pos] = k;
      }
    }
    __syncthreads();
    if (cnt >= 512u) {
      if (t == 0) gbase = atomicAdd(cursor, cnt);
      __syncthreads();
      for (unsigned i = t; i < cnt; i += blockDim.x) outbuf[gbase + i] = buf[i];
      __syncthreads();
      if (t == 0) cnt = 0u;
      __syncthreads();
    }
  }
  if (t == 0 && cnt > 0u) gbase = atomicAdd(cursor, cnt);
  __syncthreads();
  for (unsigned i = t; i < cnt; i += blockDim.x) outbuf[gbase + i] = buf[i];
}

// finish last 40 bits on the (small) compacted candidate set, single block
__global__ void __launch_bounds__(1024) k_finish(const u64* __restrict__ cb,
                                                 const unsigned* __restrict__ cur,
                                                 u64* __restrict__ state) {
  __shared__ unsigned h[1024];
  __shared__ u64 spref;
  __shared__ unsigned skrem;
  int t = threadIdx.x;
  unsigned cnt = cur[1];
  if (t == 0) { spref = state[0]; skrem = (unsigned)state[1]; }
  __syncthreads();
  for (int shift = 30; shift >= 0; shift -= 10) {
    h[t] = 0u; __syncthreads();
    u64 pref = spref;
    for (unsigned j = t; j < cnt; j += 1024) {
      u64 k = cb[j];
      if (((k ^ pref) >> (shift + 10)) == 0ull)
        atomicAdd(&h[(unsigned)((k >> shift) & 1023ull)], 1u);
    }
    __syncthreads();
    unsigned v = h[t];
    for (int off = 1; off < 1024; off <<= 1) {
      unsigned x = (t >= off) ? h[t - off] : 0u;
      __syncthreads();
      h[t] += x;
      __syncthreads();
    }
    unsigned incl = h[t], excl = incl - v;
    unsigned krem = skrem;
    __syncthreads();
    if (incl >= krem && excl < krem) {
      spref |= ((u64)t) << shift;
      skrem = krem - excl;
    }
    __syncthreads();
  }
  if (t == 0) state[0] = spref;   // exact K-th smallest key
}

// ---------------- propagate, MLP-restructured like k_cos ----------------
// 32-lane group per node = 8 edge slots x 4 dim slices; f64 accumulate.

__global__ void k_prop(const unsigned* __restrict__ rowptr, const uint2* __restrict__ csr,
                       const u64* __restrict__ key, const u64* __restrict__ state,
                       const float* __restrict__ hn, const float* __restrict__ nrm,
                       float* __restrict__ hout) {
  int t = threadIdx.x;
  int lane = t & 31;
  int sl = lane >> 2, ds = lane & 3;
  int n = blockIdx.x * 8 + (t >> 5);
  u64 X = state[0];                         // cut iff key <= X
  unsigned j0 = rowptr[n], j1 = rowptr[n + 1];
  double acc[8];
  #pragma unroll
  for (int i = 0; i < 8; i++) acc[i] = 0.0;
  for (unsigned base = j0; base < j1; base += 8) {
    unsigned j = base + sl;
    bool val = (j < j1);
    uint2 c = val ? csr[j] : make_uint2(0u, 0u);
    u64 k = val ? key[j] : 0ull;
    bool keep = val && (k > X);
    const float4* arow = (const float4*)(hn + (size_t)c.x * DI + ds * 8);
    float4 a0 = arow[0], a1 = arow[1];      // two independent gathers
    if (keep) {
      acc[0] += (double)a0.x; acc[1] += (double)a0.y;
      acc[2] += (double)a0.z; acc[3] += (double)a0.w;
      acc[4] += (double)a1.x; acc[5] += (double)a1.y;
      acc[6] += (double)a1.z; acc[7] += (double)a1.w;
    }
  }
  #pragma unroll
  for (int m = 4; m <= 16; m <<= 1) {
    #pragma unroll
    for (int i = 0; i < 8; i++) acc[i] += __shfl_xor(acc[i], m, 32);
  }
  if (sl == 0) {                            // lanes 0..3 hold dims ds*8..ds*8+7
    float nv = nrm[n];
    float4 o0, o1;
    o0.x = (float)acc[0] * nv; o0.y = (float)acc[1] * nv;
    o0.z = (float)acc[2] * nv; o0.w = (float)acc[3] * nv;
    o1.x = (float)acc[4] * nv; o1.y = (float)acc[5] * nv;
    o1.z = (float)acc[6] * nv; o1.w = (float)acc[7] * nv;
    float4* orow = (float4*)(hout + (size_t)n * DI + ds * 8);
    orow[0] = o0; orow[1] = o1;
  }
}

// ---------------- final FC: out = h @ W^T ----------------

__global__ void k_fc(const float* __restrict__ h, const float* __restrict__ W,
                     float* __restrict__ out) {
  __shared__ float Wt[DI * 65];   // Wt[d][o], padded stride 65
  __shared__ float hs[4 * DI];
  int t = threadIdx.x;
  #pragma unroll
  for (int i = 0; i < 8; i++) {
    int idx = t + i * 256;                 // idx = o*32 + d
    Wt[(idx & 31) * 65 + (idx >> 5)] = W[idx];
  }
  int n0 = blockIdx.x * 4;
  if (t < 128) hs[t] = h[n0 * DI + t];
  __syncthreads();
  int o = t & 63, nl = t >> 6;
  float acc = 0.f;
  #pragma unroll
  for (int d = 0; d < DI; d++) acc += hs[nl * DI + d] * Wt[d * 65 + o];
  out[(n0 + nl) * DO + o] = acc;
}

// ---------------- launch ----------------

extern "C" void kernel_launch(void* const* d_in, const int* in_sizes, int n_in,
                              void* d_out, int out_size, void* d_ws, size_t ws_size,
                              hipStream_t stream) {
  const float* feat = (const float*)d_in[0];
  const int*   src  = (const int*)d_in[1];
  const int*   dst  = (const int*)d_in[2];
  const float* W    = (const float*)d_in[3];
  float*       out  = (float*)d_out;

  // workspace layout (~79 MB), all u64 pointers 8B-aligned
  float* bufA = (float*)d_ws;                       // NN*DI f32
  float* bufB = bufA + (size_t)NN * DI;
  float* bufC = bufB + (size_t)NN * DI;
  u64*   key  = (u64*)(bufC + (size_t)NN * DI);     // NE u64
  u64*   cbuf2 = key + NE;                          // NE u64 (aliased: binned)
  u64*   binned = cbuf2;                            // dead before cbuf2 is used
  float*    nrm     = (float*)(cbuf2 + NE);
  unsigned* degi    = (unsigned*)(nrm + NN);
  unsigned* rowptr  = degi + NN;                    // NN+2 (pad keeps 8B alignment)
  unsigned* fill    = rowptr + NN + 2;
  unsigned* bsum    = fill + NN;                    // 128
  unsigned* hist    = bsum + 128;                   // 4096
  unsigned* cur     = hist + 4096;                  // 2
  u64*      state   = (u64*)(cur + 2);              // 2
  uint2*    csr     = (uint2*)(state + 2);          // NE uint2
  unsigned* bhist   = (unsigned*)(csr + NE);        // 128
  unsigned* bstart  = bhist + 128;                  // NB+1 (pad to 100)
  unsigned* bcur    = bstart + 100;                 // 128

  // ---- binned CSR build (edges are hop-invariant) ----
  k_zero_u32<<<1, 128, 0, stream>>>(bhist, 128);
  k_bhist<<<512, 256, 0, stream>>>(dst, bhist);
  k_bscan<<<1, 1, 0, stream>>>(bhist, bstart, bcur);
  k_bin<<<(NE + CH - 1) / CH, 256, 0, stream>>>(src, dst, bcur, binned);
  k_bucket_deg<<<NB, 256, 0, stream>>>(binned, bstart, degi);
  k_norm<<<(NN + 255) / 256, 256, 0, stream>>>(degi, nrm);
  int nb = (NN + 1023) / 1024;   // 98
  k_psum_a<<<nb, 1024, 0, stream>>>(degi, bsum);
  k_psum_b<<<1, 1, 0, stream>>>(bsum, nb, rowptr);
  k_psum_c<<<nb, 1024, 0, stream>>>(degi, bsum, rowptr, fill);
  k_bucket_scatter<<<NB, 256, 0, stream>>>(binned, bstart, fill, csr);

  // hop 0: nh=A, hn=B, out=A, cbuf1=C   |   hop 1: nh=C, hn=B, out=C, cbuf1=A
  const float* hin = feat;
  for (int hop = 0; hop < 2; hop++) {
    float* nh = (hop == 0) ? bufA : bufC;
    float* hn = bufB;
    float* ho = (hop == 0) ? bufA : bufC;
    u64* cbuf1 = (u64*)((hop == 0) ? bufC : bufA);  // free this hop

    k_rownorm<<<NN / 8, 256, 0, stream>>>(hin, nrm, nh, hn);
    k_radix_init<<<1, 256, 0, stream>>>(hist, state, cur);
    k_cos<<<NN / 8, 256, 0, stream>>>(rowptr, csr, nh, key, hist);

    k_select<<<1, 256, 0, stream>>>(hist, state, 52);
    k_compact<<<512, 256, 0, stream>>>(key, nullptr, NE, state, 52, cbuf1, cur + 0);
    k_hist<<<64, 256, 0, stream>>>(cbuf1, cur + 0, 0, state, hist, 40, 0);
    k_select<<<1, 256, 0, stream>>>(hist, state, 40);
    k_compact<<<64, 256, 0, stream>>>(cbuf1, cur + 0, 0, state, 40, cbuf2, cur + 1);
    k_finish<<<1, 1024, 0, stream>>>(cbuf2, cur, state);

    k_prop<<<NN / 8, 256, 0, stream>>>(rowptr, csr, key, state, hn, nrm, ho);
    hin = ho;
  }
  k_fc<<<NN / 4, 256, 0, stream>>>(hin, W, out);
}

// Round 8
// 512.428 us; speedup vs baseline: 1.7154x; 1.7154x over previous
//
#include <hip/hip_runtime.h>

// SGC layer: N=100000 nodes, E=1600000 edges, D_IN=32, D_OUT=64, 2 hops,
// per-hop cut of the 160000 lowest-cosine edges (exact top-k w/ index ties).

constexpr int NN   = 100000;
constexpr int NE   = 1600000;
constexpr int DI   = 32;
constexpr int DO   = 64;
constexpr int KCUT = 160000;
constexpr int NB   = 98;      // buckets of 1024 node-ids (ceil(100000/1024))
constexpr int CH   = 4096;    // edges per bin chunk
constexpr int HB   = 256;     // blocks for the big histogram (dense private hists)

typedef unsigned long long u64;

// ---------------- utility ----------------

__global__ void k_zero_u32(unsigned* p, int n) {
  int i = blockIdx.x * blockDim.x + threadIdx.x;
  if (i < n) p[i] = 0u;
}

__global__ void k_norm(const unsigned* __restrict__ degi, float* __restrict__ nrm) {
  int i = blockIdx.x * blockDim.x + threadIdx.x;
  if (i < NN) {
    unsigned d = degi[i]; if (d < 1u) d = 1u;
    nrm[i] = (float)(1.0 / sqrt((double)d));   // == pow(deg, -0.5)
  }
}

// ---------------- binned CSR build ----------------
// packed edge: bits 38-47 dloc (dst & 1023), 21-37 src, 0-20 eid

__global__ void k_bhist(const int* __restrict__ dst, unsigned* __restrict__ bhist) {
  __shared__ unsigned lh[128];
  int t = threadIdx.x;
  if (t < 128) lh[t] = 0u;
  __syncthreads();
  int stride = gridDim.x * blockDim.x;
  for (int e = blockIdx.x * blockDim.x + t; e < NE; e += stride)
    atomicAdd(&lh[((unsigned)dst[e]) >> 10], 1u);
  __syncthreads();
  if (t < 128 && lh[t]) atomicAdd(&bhist[t], lh[t]);
}

__global__ void k_bscan(const unsigned* __restrict__ bhist, unsigned* __restrict__ bstart,
                        unsigned* __restrict__ bcur) {
  if (threadIdx.x == 0 && blockIdx.x == 0) {
    unsigned run = 0;
    for (int b = 0; b < NB; b++) { bstart[b] = run; bcur[b] = run; run += bhist[b]; }
    bstart[NB] = run;   // == NE
  }
}

// block-aggregated multisplit: one global atomic per (bucket, chunk)
__global__ void k_bin(const int* __restrict__ src, const int* __restrict__ dst,
                      unsigned* __restrict__ bcur, u64* __restrict__ binned) {
  __shared__ unsigned h1[128], h2[128], res[128];
  int t = threadIdx.x;
  for (int base = blockIdx.x * CH; base < NE; base += gridDim.x * CH) {
    int nE = min(CH, NE - base);
    if (t < 128) h1[t] = 0u;
    __syncthreads();
    for (int i = t; i < nE; i += 256)
      atomicAdd(&h1[((unsigned)dst[base + i]) >> 10], 1u);
    __syncthreads();
    if (t < 128) { unsigned c = h1[t]; res[t] = c ? atomicAdd(&bcur[t], c) : 0u; h2[t] = 0u; }
    __syncthreads();
    for (int i = t; i < nE; i += 256) {   // chunk re-read hits L1/L2
      unsigned d = (unsigned)dst[base + i];
      unsigned bb = d >> 10;
      u64 pk = ((u64)(d & 1023u) << 38) | ((u64)(unsigned)src[base + i] << 21)
             | (u64)(unsigned)(base + i);
      unsigned r = atomicAdd(&h2[bb], 1u);
      binned[res[bb] + r] = pk;
    }
    __syncthreads();
  }
}

// per-bucket degree count in LDS -> coalesced degi write
__global__ void k_bucket_deg(const u64* __restrict__ binned, const unsigned* __restrict__ bstart,
                             unsigned* __restrict__ degi) {
  __shared__ unsigned cnt[1024];
  int t = threadIdx.x;
  int b = blockIdx.x;
  for (int i = t; i < 1024; i += 256) cnt[i] = 0u;
  __syncthreads();
  unsigned j0 = bstart[b], j1 = bstart[b + 1];
  for (unsigned j = j0 + t; j < j1; j += 256)
    atomicAdd(&cnt[(unsigned)(binned[j] >> 38)], 1u);
  __syncthreads();
  int base = b << 10;
  for (int i = t; i < 1024; i += 256)
    if (base + i < NN) degi[base + i] = cnt[i];
}

// per-bucket scatter: fill atomics hit a 4KB region, csr writes ~130KB (L2-hot)
__global__ void k_bucket_scatter(const u64* __restrict__ binned, const unsigned* __restrict__ bstart,
                                 unsigned* __restrict__ fill, uint2* __restrict__ csr) {
  int t = threadIdx.x;
  int b = blockIdx.x;
  unsigned j0 = bstart[b], j1 = bstart[b + 1];
  int base = b << 10;
  for (unsigned j = j0 + t; j < j1; j += 256) {
    u64 pk = binned[j];
    unsigned dloc = (unsigned)(pk >> 38);
    unsigned s = (unsigned)((pk >> 21) & 0x1FFFFu);
    unsigned e = (unsigned)(pk & 0x1FFFFFu);
    unsigned g = atomicAdd(&fill[base + dloc], 1u);
    csr[g] = make_uint2(s, e);
  }
}

// ---------------- prefix sum (rowptr) ----------------

__global__ void k_psum_a(const unsigned* __restrict__ degi, unsigned* __restrict__ bsum) {
  __shared__ unsigned s[1024];
  int t = threadIdx.x;
  int i = blockIdx.x * 1024 + t;
  s[t] = (i < NN) ? degi[i] : 0u;
  __syncthreads();
  for (int off = 512; off > 0; off >>= 1) {
    if (t < off) s[t] += s[t + off];
    __syncthreads();
  }
  if (t == 0) bsum[blockIdx.x] = s[0];
}

__global__ void k_psum_b(unsigned* bsum, int nb, unsigned* rowptr) {
  if (threadIdx.x == 0 && blockIdx.x == 0) {
    unsigned run = 0;
    for (int b = 0; b < nb; b++) { unsigned v = bsum[b]; bsum[b] = run; run += v; }
    rowptr[NN] = run;   // == NE
  }
}

__global__ void k_psum_c(const unsigned* __restrict__ degi, const unsigned* __restrict__ bsum,
                         unsigned* __restrict__ rowptr, unsigned* __restrict__ fill) {
  __shared__ unsigned s[1024];
  int t = threadIdx.x;
  int i = blockIdx.x * 1024 + t;
  unsigned v = (i < NN) ? degi[i] : 0u;
  s[t] = v; __syncthreads();
  for (int off = 1; off < 1024; off <<= 1) {
    unsigned x = (t >= off) ? s[t - off] : 0u;
    __syncthreads();
    s[t] += x;
    __syncthreads();
  }
  if (i < NN) {
    unsigned excl = bsum[blockIdx.x] + s[t] - v;
    rowptr[i] = excl;
    fill[i]   = excl;
  }
}

// ---------------- per-hop kernels ----------------

// 8 nodes per 256-thread block; lane = feature dim
__global__ void k_rownorm(const float* __restrict__ h, const float* __restrict__ nrm,
                          float* __restrict__ nh, float* __restrict__ hn) {
  int lane = threadIdx.x & 31;
  int n = blockIdx.x * 8 + (threadIdx.x >> 5);
  float v = h[n * DI + lane];
  double sq = (double)v * (double)v;
  #pragma unroll
  for (int m = 16; m > 0; m >>= 1) sq += __shfl_xor(sq, m, 32);
  double den = sqrt(sq);
  if (den < 1e-12) den = 1e-12;
  nh[n * DI + lane] = (float)((double)v / den);
  hn[n * DI + lane] = v * nrm[n];
}

// cosine, MLP-restructured, PURE (no LDS, no atomics): 32-lane group per node
// = 8 edge slots x 4 dim slices; 16 independent float4 gathers in flight.
__global__ void k_cos(const unsigned* __restrict__ rowptr, const uint2* __restrict__ csr,
                      const float* __restrict__ nh, u64* __restrict__ key) {
  int t = threadIdx.x;
  int lane = t & 31;
  int sl = lane >> 2;        // edge slot 0..7
  int ds = lane & 3;         // dim slice 0..3 (8 dims each)
  int n = blockIdx.x * 8 + (t >> 5);
  const float4* drow = (const float4*)(nh + (size_t)n * DI + ds * 8);
  float4 d0 = drow[0], d1 = drow[1];
  unsigned j0 = rowptr[n], j1 = rowptr[n + 1];
  for (unsigned base = j0; base < j1; base += 8) {
    unsigned j = base + sl;
    bool val = (j < j1);
    uint2 c = val ? csr[j] : make_uint2(0u, 0u);
    const float4* arow = (const float4*)(nh + (size_t)c.x * DI + ds * 8);
    float4 a0 = arow[0], a1 = arow[1];   // two independent gathers
    double p = (double)a0.x * d0.x + (double)a0.y * d0.y
             + (double)a0.z * d0.z + (double)a0.w * d0.w
             + (double)a1.x * d1.x + (double)a1.y * d1.y
             + (double)a1.z * d1.z + (double)a1.w * d1.w;
    p += __shfl_xor(p, 1, 32);
    p += __shfl_xor(p, 2, 32);
    if (val && ds == 0) {
      float cf = (float)p;
      unsigned u = __float_as_uint(cf);
      u = (u & 0x80000000u) ? ~u : (u | 0x80000000u);   // monotone float->uint
      key[j] = ((u64)u << 32) | (u64)c.y;
    }
  }
}

// ---------------- radix select (K-th smallest 64-bit key) ----------------
// state[0] = prefix (becomes the K-th smallest key), state[1] = k remaining

__global__ void k_radix_init(u64* state, unsigned* cur) {
  if (threadIdx.x == 0) { state[0] = 0ull; state[1] = (u64)KCUT; cur[0] = 0u; cur[1] = 0u; }
}

// big histogram, atomic-free merge: dense private LDS hist per block ->
// coalesced dump to ghist[block][4096]
__global__ void k_hist_big(const u64* __restrict__ keys, unsigned* __restrict__ ghist) {
  __shared__ unsigned lh[4096];
  int t = threadIdx.x;
  for (int i = t; i < 4096; i += 256) lh[i] = 0u;
  __syncthreads();
  int stride = gridDim.x * blockDim.x;
  for (int j = blockIdx.x * blockDim.x + t; j < NE; j += stride)
    atomicAdd(&lh[(unsigned)(keys[j] >> 52)], 1u);
  __syncthreads();
  unsigned* gh = ghist + (size_t)blockIdx.x * 4096;
  for (int i = t; i < 4096; i += 256) gh[i] = lh[i];
}

// column-sum ghist -> hist (coalesced: consecutive threads read consecutive bins)
__global__ void k_hist_reduce(const unsigned* __restrict__ ghist, unsigned* __restrict__ hist) {
  int bin = blockIdx.x * 256 + threadIdx.x;   // 16 blocks x 256
  unsigned s = 0;
  for (int b = 0; b < HB; b++) s += ghist[(size_t)b * 4096 + bin];
  hist[bin] = s;
}

// small histogram (candidate set, sparse): LDS + atomic merge of nonzero bins
// check==0 -> NO prefix test (candidate buffer already prefix-filtered)
__global__ void k_hist(const u64* __restrict__ keys, const unsigned* __restrict__ cntp,
                       const u64* __restrict__ state,
                       unsigned* __restrict__ hist, int shift, int check) {
  __shared__ unsigned lh[4096];
  int t = threadIdx.x;
  for (int i = t; i < 4096; i += 256) lh[i] = 0u;
  __syncthreads();
  int n = (int)*cntp;
  u64 pref = state[0];
  int stride = gridDim.x * blockDim.x;
  for (int j = blockIdx.x * blockDim.x + t; j < n; j += stride) {
    u64 k = keys[j];
    bool ok = (check == 0) || (((k ^ pref) >> check) == 0ull);
    if (ok) atomicAdd(&lh[(unsigned)((k >> shift) & 4095ull)], 1u);
  }
  __syncthreads();
  for (int i = t; i < 4096; i += 256) if (lh[i]) atomicAdd(&hist[i], lh[i]);
}

// scan 4096 bins, pick bucket containing krem-th element, zero hist for reuse
__global__ void k_select(unsigned* hist, u64* state, int shift) {
  __shared__ unsigned ssum[256];
  int t = threadIdx.x;
  unsigned loc[16]; unsigned tot = 0;
  #pragma unroll
  for (int i = 0; i < 16; i++) { loc[i] = hist[t * 16 + i]; tot += loc[i]; }
  #pragma unroll
  for (int i = 0; i < 16; i++) hist[t * 16 + i] = 0u;
  unsigned krem = (unsigned)state[1];
  ssum[t] = tot; __syncthreads();
  for (int off = 1; off < 256; off <<= 1) {
    unsigned x = (t >= off) ? ssum[t - off] : 0u;
    __syncthreads();
    ssum[t] += x;
    __syncthreads();
  }
  unsigned incl = ssum[t], excl = incl - tot;
  if (incl >= krem && excl < krem) {
    unsigned run = excl; int b = 0; unsigned nk = 0;
    #pragma unroll
    for (int i = 0; i < 16; i++) {
      if (krem <= run + loc[i]) { b = t * 16 + i; nk = krem - run; break; }
      run += loc[i];
    }
    state[0] |= ((u64)b) << shift;
    state[1] = (u64)nk;
  }
}

// block-aggregated compaction: LDS staging + one global atomic per flush
__global__ void k_compact(const u64* __restrict__ keys, const unsigned* __restrict__ cntp,
                          int n_fixed, const u64* __restrict__ state, int check,
                          u64* __restrict__ outbuf, unsigned* __restrict__ cursor) {
  __shared__ u64 buf[768];
  __shared__ unsigned cnt, gbase;
  int t = threadIdx.x;
  if (t == 0) cnt = 0u;
  __syncthreads();
  int n = cntp ? (int)*cntp : n_fixed;
  u64 pref = state[0];
  int stride = gridDim.x * blockDim.x;
  for (int j0 = blockIdx.x * blockDim.x; j0 < n; j0 += stride) {
    int j = j0 + t;
    if (j < n) {
      u64 k = keys[j];
      if (((k ^ pref) >> check) == 0ull) {
        unsigned pos = atomicAdd(&cnt, 1u);
        buf[pos] = k;
      }
    }
    __syncthreads();
    if (cnt >= 512u) {
      if (t == 0) gbase = atomicAdd(cursor, cnt);
      __syncthreads();
      for (unsigned i = t; i < cnt; i += blockDim.x) outbuf[gbase + i] = buf[i];
      __syncthreads();
      if (t == 0) cnt = 0u;
      __syncthreads();
    }
  }
  if (t == 0 && cnt > 0u) gbase = atomicAdd(cursor, cnt);
  __syncthreads();
  for (unsigned i = t; i < cnt; i += blockDim.x) outbuf[gbase + i] = buf[i];
}

// finish last 40 bits on the (small) compacted candidate set, single block
__global__ void __launch_bounds__(1024) k_finish(const u64* __restrict__ cb,
                                                 const unsigned* __restrict__ cur,
                                                 u64* __restrict__ state) {
  __shared__ unsigned h[1024];
  __shared__ u64 spref;
  __shared__ unsigned skrem;
  int t = threadIdx.x;
  unsigned cnt = cur[1];
  if (t == 0) { spref = state[0]; skrem = (unsigned)state[1]; }
  __syncthreads();
  for (int shift = 30; shift >= 0; shift -= 10) {
    h[t] = 0u; __syncthreads();
    u64 pref = spref;
    for (unsigned j = t; j < cnt; j += 1024) {
      u64 k = cb[j];
      if (((k ^ pref) >> (shift + 10)) == 0ull)
        atomicAdd(&h[(unsigned)((k >> shift) & 1023ull)], 1u);
    }
    __syncthreads();
    unsigned v = h[t];
    for (int off = 1; off < 1024; off <<= 1) {
      unsigned x = (t >= off) ? h[t - off] : 0u;
      __syncthreads();
      h[t] += x;
      __syncthreads();
    }
    unsigned incl = h[t], excl = incl - v;
    unsigned krem = skrem;
    __syncthreads();
    if (incl >= krem && excl < krem) {
      spref |= ((u64)t) << shift;
      skrem = krem - excl;
    }
    __syncthreads();
  }
  if (t == 0) state[0] = spref;   // exact K-th smallest key
}

// ---------------- propagate, MLP-restructured like k_cos ----------------
// 32-lane group per node = 8 edge slots x 4 dim slices; f64 accumulate.

__global__ void k_prop(const unsigned* __restrict__ rowptr, const uint2* __restrict__ csr,
                       const u64* __restrict__ key, const u64* __restrict__ state,
                       const float* __restrict__ hn, const float* __restrict__ nrm,
                       float* __restrict__ hout) {
  int t = threadIdx.x;
  int lane = t & 31;
  int sl = lane >> 2, ds = lane & 3;
  int n = blockIdx.x * 8 + (t >> 5);
  u64 X = state[0];                         // cut iff key <= X
  unsigned j0 = rowptr[n], j1 = rowptr[n + 1];
  double acc[8];
  #pragma unroll
  for (int i = 0; i < 8; i++) acc[i] = 0.0;
  for (unsigned base = j0; base < j1; base += 8) {
    unsigned j = base + sl;
    bool val = (j < j1);
    uint2 c = val ? csr[j] : make_uint2(0u, 0u);
    u64 k = val ? key[j] : 0ull;
    bool keep = val && (k > X);
    const float4* arow = (const float4*)(hn + (size_t)c.x * DI + ds * 8);
    float4 a0 = arow[0], a1 = arow[1];      // two independent gathers
    if (keep) {
      acc[0] += (double)a0.x; acc[1] += (double)a0.y;
      acc[2] += (double)a0.z; acc[3] += (double)a0.w;
      acc[4] += (double)a1.x; acc[5] += (double)a1.y;
      acc[6] += (double)a1.z; acc[7] += (double)a1.w;
    }
  }
  #pragma unroll
  for (int m = 4; m <= 16; m <<= 1) {
    #pragma unroll
    for (int i = 0; i < 8; i++) acc[i] += __shfl_xor(acc[i], m, 32);
  }
  if (sl == 0) {                            // lanes 0..3 hold dims ds*8..ds*8+7
    float nv = nrm[n];
    float4 o0, o1;
    o0.x = (float)acc[0] * nv; o0.y = (float)acc[1] * nv;
    o0.z = (float)acc[2] * nv; o0.w = (float)acc[3] * nv;
    o1.x = (float)acc[4] * nv; o1.y = (float)acc[5] * nv;
    o1.z = (float)acc[6] * nv; o1.w = (float)acc[7] * nv;
    float4* orow = (float4*)(hout + (size_t)n * DI + ds * 8);
    orow[0] = o0; orow[1] = o1;
  }
}

// ---------------- final FC: out = h @ W^T ----------------

__global__ void k_fc(const float* __restrict__ h, const float* __restrict__ W,
                     float* __restrict__ out) {
  __shared__ float Wt[DI * 65];   // Wt[d][o], padded stride 65
  __shared__ float hs[4 * DI];
  int t = threadIdx.x;
  #pragma unroll
  for (int i = 0; i < 8; i++) {
    int idx = t + i * 256;                 // idx = o*32 + d
    Wt[(idx & 31) * 65 + (idx >> 5)] = W[idx];
  }
  int n0 = blockIdx.x * 4;
  if (t < 128) hs[t] = h[n0 * DI + t];
  __syncthreads();
  int o = t & 63, nl = t >> 6;
  float acc = 0.f;
  #pragma unroll
  for (int d = 0; d < DI; d++) acc += hs[nl * DI + d] * Wt[d * 65 + o];
  out[(n0 + nl) * DO + o] = acc;
}

// ---------------- launch ----------------

extern "C" void kernel_launch(void* const* d_in, const int* in_sizes, int n_in,
                              void* d_out, int out_size, void* d_ws, size_t ws_size,
                              hipStream_t stream) {
  const float* feat = (const float*)d_in[0];
  const int*   src  = (const int*)d_in[1];
  const int*   dst  = (const int*)d_in[2];
  const float* W    = (const float*)d_in[3];
  float*       out  = (float*)d_out;

  // workspace layout (~79 MB), all u64 pointers 8B-aligned
  float* bufA = (float*)d_ws;                       // NN*DI f32
  float* bufB = bufA + (size_t)NN * DI;
  float* bufC = bufB + (size_t)NN * DI;
  u64*   key  = (u64*)(bufC + (size_t)NN * DI);     // NE u64
  u64*   cbuf2 = key + NE;                          // NE u64 (aliased: binned, ghist)
  u64*   binned = cbuf2;                            // dead before cbuf2 is used
  unsigned* ghist = (unsigned*)cbuf2;               // HB*4096 u32 = 4MB, dead before cbuf2
  float*    nrm     = (float*)(cbuf2 + NE);
  unsigned* degi    = (unsigned*)(nrm + NN);
  unsigned* rowptr  = degi + NN;                    // NN+2 (pad keeps 8B alignment)
  unsigned* fill    = rowptr + NN + 2;
  unsigned* bsum    = fill + NN;                    // 128
  unsigned* hist    = bsum + 128;                   // 4096
  unsigned* cur     = hist + 4096;                  // 2
  u64*      state   = (u64*)(cur + 2);              // 2
  uint2*    csr     = (uint2*)(state + 2);          // NE uint2
  unsigned* bhist   = (unsigned*)(csr + NE);        // 128
  unsigned* bstart  = bhist + 128;                  // NB+1 (pad to 100)
  unsigned* bcur    = bstart + 100;                 // 128

  // ---- binned CSR build (edges are hop-invariant) ----
  k_zero_u32<<<1, 128, 0, stream>>>(bhist, 128);
  k_bhist<<<512, 256, 0, stream>>>(dst, bhist);
  k_bscan<<<1, 1, 0, stream>>>(bhist, bstart, bcur);
  k_bin<<<(NE + CH - 1) / CH, 256, 0, stream>>>(src, dst, bcur, binned);
  k_bucket_deg<<<NB, 256, 0, stream>>>(binned, bstart, degi);
  k_norm<<<(NN + 255) / 256, 256, 0, stream>>>(degi, nrm);
  int nb = (NN + 1023) / 1024;   // 98
  k_psum_a<<<nb, 1024, 0, stream>>>(degi, bsum);
  k_psum_b<<<1, 1, 0, stream>>>(bsum, nb, rowptr);
  k_psum_c<<<nb, 1024, 0, stream>>>(degi, bsum, rowptr, fill);
  k_bucket_scatter<<<NB, 256, 0, stream>>>(binned, bstart, fill, csr);

  // hop 0: nh=A, hn=B, out=A, cbuf1=C   |   hop 1: nh=C, hn=B, out=C, cbuf1=A
  const float* hin = feat;
  for (int hop = 0; hop < 2; hop++) {
    float* nh = (hop == 0) ? bufA : bufC;
    float* hn = bufB;
    float* ho = (hop == 0) ? bufA : bufC;
    u64* cbuf1 = (u64*)((hop == 0) ? bufC : bufA);  // free this hop

    k_rownorm<<<NN / 8, 256, 0, stream>>>(hin, nrm, nh, hn);
    k_cos<<<NN / 8, 256, 0, stream>>>(rowptr, csr, nh, key);

    k_radix_init<<<1, 64, 0, stream>>>(state, cur);
    k_hist_big<<<HB, 256, 0, stream>>>(key, ghist);           // atomic-free merge
    k_hist_reduce<<<16, 256, 0, stream>>>(ghist, hist);
    k_select<<<1, 256, 0, stream>>>(hist, state, 52);
    k_compact<<<512, 256, 0, stream>>>(key, nullptr, NE, state, 52, cbuf1, cur + 0);
    k_hist<<<64, 256, 0, stream>>>(cbuf1, cur + 0, state, hist, 40, 0);
    k_select<<<1, 256, 0, stream>>>(hist, state, 40);
    k_compact<<<64, 256, 0, stream>>>(cbuf1, cur + 0, 0, state, 40, cbuf2, cur + 1);
    k_finish<<<1, 1024, 0, stream>>>(cbuf2, cur, state);

    k_prop<<<NN / 8, 256, 0, stream>>>(rowptr, csr, key, state, hn, nrm, ho);
    hin = ho;
  }
  k_fc<<<NN / 4, 256, 0, stream>>>(hin, W, out);
}

// Round 9
// 472.084 us; speedup vs baseline: 1.8620x; 1.0855x over previous
//
#include <hip/hip_runtime.h>

// SGC layer: N=100000 nodes, E=1600000 edges, D_IN=32, D_OUT=64, 2 hops,
// per-hop cut of the 160000 lowest-cosine edges (exact top-k w/ index ties).

constexpr int NN   = 100000;
constexpr int NE   = 1600000;
constexpr int DI   = 32;
constexpr int DO   = 64;
constexpr int KCUT = 160000;
constexpr int NB   = 98;      // buckets of 1024 node-ids (ceil(100000/1024))
constexpr int CH   = 4096;    // edges per bin chunk
constexpr int HB   = 256;     // blocks for the big histogram (dense private hists)
constexpr int SCAP = 19456;   // LDS staging capacity (edges/bucket); mean 16384, +5sigma ~= 17000

typedef unsigned long long u64;

// ---------------- utility ----------------

__global__ void k_zero_u32(unsigned* p, int n) {
  int i = blockIdx.x * blockDim.x + threadIdx.x;
  if (i < n) p[i] = 0u;
}

__global__ void k_norm(const unsigned* __restrict__ degi, float* __restrict__ nrm) {
  int i = blockIdx.x * blockDim.x + threadIdx.x;
  if (i < NN) {
    unsigned d = degi[i]; if (d < 1u) d = 1u;
    nrm[i] = (float)(1.0 / sqrt((double)d));   // == pow(deg, -0.5)
  }
}

// ---------------- binned CSR build ----------------
// packed edge: bits 38-47 dloc (dst & 1023), 21-37 src, 0-20 eid

__global__ void k_bhist(const int* __restrict__ dst, unsigned* __restrict__ bhist) {
  __shared__ unsigned lh[128];
  int t = threadIdx.x;
  if (t < 128) lh[t] = 0u;
  __syncthreads();
  int stride = gridDim.x * blockDim.x;
  for (int e = blockIdx.x * blockDim.x + t; e < NE; e += stride)
    atomicAdd(&lh[((unsigned)dst[e]) >> 10], 1u);
  __syncthreads();
  if (t < 128 && lh[t]) atomicAdd(&bhist[t], lh[t]);
}

__global__ void k_bscan(const unsigned* __restrict__ bhist, unsigned* __restrict__ bstart,
                        unsigned* __restrict__ bcur) {
  if (threadIdx.x == 0 && blockIdx.x == 0) {
    unsigned run = 0;
    for (int b = 0; b < NB; b++) { bstart[b] = run; bcur[b] = run; run += bhist[b]; }
    bstart[NB] = run;   // == NE
  }
}

// block-aggregated multisplit: one global atomic per (bucket, chunk)
__global__ void k_bin(const int* __restrict__ src, const int* __restrict__ dst,
                      unsigned* __restrict__ bcur, u64* __restrict__ binned) {
  __shared__ unsigned h1[128], h2[128], res[128];
  int t = threadIdx.x;
  for (int base = blockIdx.x * CH; base < NE; base += gridDim.x * CH) {
    int nE = min(CH, NE - base);
    if (t < 128) h1[t] = 0u;
    __syncthreads();
    for (int i = t; i < nE; i += 256)
      atomicAdd(&h1[((unsigned)dst[base + i]) >> 10], 1u);
    __syncthreads();
    if (t < 128) { unsigned c = h1[t]; res[t] = c ? atomicAdd(&bcur[t], c) : 0u; h2[t] = 0u; }
    __syncthreads();
    for (int i = t; i < nE; i += 256) {   // chunk re-read hits L1/L2
      unsigned d = (unsigned)dst[base + i];
      unsigned bb = d >> 10;
      u64 pk = ((u64)(d & 1023u) << 38) | ((u64)(unsigned)src[base + i] << 21)
             | (u64)(unsigned)(base + i);
      unsigned r = atomicAdd(&h2[bb], 1u);
      binned[res[bb] + r] = pk;
    }
    __syncthreads();
  }
}

// per-bucket degree count in LDS -> coalesced degi write
__global__ void k_bucket_deg(const u64* __restrict__ binned, const unsigned* __restrict__ bstart,
                             unsigned* __restrict__ degi) {
  __shared__ unsigned cnt[1024];
  int t = threadIdx.x;
  int b = blockIdx.x;
  for (int i = t; i < 1024; i += 256) cnt[i] = 0u;
  __syncthreads();
  unsigned j0 = bstart[b], j1 = bstart[b + 1];
  for (unsigned j = j0 + t; j < j1; j += 256)
    atomicAdd(&cnt[(unsigned)(binned[j] >> 38)], 1u);
  __syncthreads();
  int base = b << 10;
  for (int i = t; i < 1024; i += 256)
    if (base + i < NN) degi[base + i] = cnt[i];
}

// LDS-staged bucket scatter: scatter lands in LDS, global write is one
// coalesced streaming copy (was: random 8B global stores -> 80MB writeback).
// Dynamic LDS: 1024 u32 cursors + SCAP u64 staging slots (~156KB).
__global__ void k_bucket_scatter(const u64* __restrict__ binned, const unsigned* __restrict__ bstart,
                                 const unsigned* __restrict__ rowptr, uint2* __restrict__ csr) {
  extern __shared__ unsigned smem[];
  unsigned* curl = smem;                    // 1024 cursors (local offsets)
  u64* stage = (u64*)(smem + 1024);         // SCAP entries
  int t = threadIdx.x;
  int b = blockIdx.x;
  unsigned j0 = bstart[b], j1 = bstart[b + 1];
  int base = b << 10;
  for (int i = t; i < 1024; i += 256)
    curl[i] = (base + i < NN) ? (rowptr[base + i] - j0) : 0u;
  __syncthreads();
  for (unsigned j = j0 + t; j < j1; j += 256) {
    u64 pk = binned[j];
    unsigned dloc = (unsigned)(pk >> 38);
    unsigned s = (unsigned)((pk >> 21) & 0x1FFFFu);
    unsigned e = (unsigned)(pk & 0x1FFFFFu);
    unsigned p = atomicAdd(&curl[dloc], 1u);
    u64 entry = ((u64)e << 32) | (u64)s;    // uint2{x=src, y=eid} little-endian
    if (p < (unsigned)SCAP) stage[p] = entry;
    else csr[j0 + p] = make_uint2(s, e);    // statistical-overflow fallback
  }
  __syncthreads();
  unsigned cnt = j1 - j0;
  u64* gout = (u64*)(csr + j0);
  for (unsigned i = t; i < cnt; i += 256)
    if (i < (unsigned)SCAP) gout[i] = stage[i];
}

// ---------------- prefix sum (rowptr) ----------------

__global__ void k_psum_a(const unsigned* __restrict__ degi, unsigned* __restrict__ bsum) {
  __shared__ unsigned s[1024];
  int t = threadIdx.x;
  int i = blockIdx.x * 1024 + t;
  s[t] = (i < NN) ? degi[i] : 0u;
  __syncthreads();
  for (int off = 512; off > 0; off >>= 1) {
    if (t < off) s[t] += s[t + off];
    __syncthreads();
  }
  if (t == 0) bsum[blockIdx.x] = s[0];
}

__global__ void k_psum_b(unsigned* bsum, int nb, unsigned* rowptr) {
  if (threadIdx.x == 0 && blockIdx.x == 0) {
    unsigned run = 0;
    for (int b = 0; b < nb; b++) { unsigned v = bsum[b]; bsum[b] = run; run += v; }
    rowptr[NN] = run;   // == NE
  }
}

__global__ void k_psum_c(const unsigned* __restrict__ degi, const unsigned* __restrict__ bsum,
                         unsigned* __restrict__ rowptr) {
  __shared__ unsigned s[1024];
  int t = threadIdx.x;
  int i = blockIdx.x * 1024 + t;
  unsigned v = (i < NN) ? degi[i] : 0u;
  s[t] = v; __syncthreads();
  for (int off = 1; off < 1024; off <<= 1) {
    unsigned x = (t >= off) ? s[t - off] : 0u;
    __syncthreads();
    s[t] += x;
    __syncthreads();
  }
  if (i < NN) rowptr[i] = bsum[blockIdx.x] + s[t] - v;
}

// ---------------- per-hop kernels ----------------

// 8 nodes per 256-thread block; lane = feature dim
__global__ void k_rownorm(const float* __restrict__ h, const float* __restrict__ nrm,
                          float* __restrict__ nh, float* __restrict__ hn) {
  int lane = threadIdx.x & 31;
  int n = blockIdx.x * 8 + (threadIdx.x >> 5);
  float v = h[n * DI + lane];
  double sq = (double)v * (double)v;
  #pragma unroll
  for (int m = 16; m > 0; m >>= 1) sq += __shfl_xor(sq, m, 32);
  double den = sqrt(sq);
  if (den < 1e-12) den = 1e-12;
  nh[n * DI + lane] = (float)((double)v / den);
  hn[n * DI + lane] = v * nrm[n];
}

// cosine, MLP-restructured, PURE (no LDS, no atomics): 32-lane group per node
// = 8 edge slots x 4 dim slices; 16 independent float4 gathers in flight.
__global__ void k_cos(const unsigned* __restrict__ rowptr, const uint2* __restrict__ csr,
                      const float* __restrict__ nh, u64* __restrict__ key) {
  int t = threadIdx.x;
  int lane = t & 31;
  int sl = lane >> 2;        // edge slot 0..7
  int ds = lane & 3;         // dim slice 0..3 (8 dims each)
  int n = blockIdx.x * 8 + (t >> 5);
  const float4* drow = (const float4*)(nh + (size_t)n * DI + ds * 8);
  float4 d0 = drow[0], d1 = drow[1];
  unsigned j0 = rowptr[n], j1 = rowptr[n + 1];
  for (unsigned base = j0; base < j1; base += 8) {
    unsigned j = base + sl;
    bool val = (j < j1);
    uint2 c = val ? csr[j] : make_uint2(0u, 0u);
    const float4* arow = (const float4*)(nh + (size_t)c.x * DI + ds * 8);
    float4 a0 = arow[0], a1 = arow[1];   // two independent gathers
    double p = (double)a0.x * d0.x + (double)a0.y * d0.y
             + (double)a0.z * d0.z + (double)a0.w * d0.w
             + (double)a1.x * d1.x + (double)a1.y * d1.y
             + (double)a1.z * d1.z + (double)a1.w * d1.w;
    p += __shfl_xor(p, 1, 32);
    p += __shfl_xor(p, 2, 32);
    if (val && ds == 0) {
      float cf = (float)p;
      unsigned u = __float_as_uint(cf);
      u = (u & 0x80000000u) ? ~u : (u | 0x80000000u);   // monotone float->uint
      key[j] = ((u64)u << 32) | (u64)c.y;
    }
  }
}

// ---------------- radix select (K-th smallest 64-bit key) ----------------
// state[0] = prefix (becomes the K-th smallest key), state[1] = k remaining

// big histogram, atomic-free merge: dense private LDS hist per block ->
// coalesced dump to ghist[block][4096]. Block 0 also re-inits radix state.
__global__ void k_hist_big(const u64* __restrict__ keys, unsigned* __restrict__ ghist,
                           u64* state, unsigned* cur) {
  __shared__ unsigned lh[4096];
  int t = threadIdx.x;
  if (blockIdx.x == 0 && t == 0) {
    state[0] = 0ull; state[1] = (u64)KCUT; cur[0] = 0u; cur[1] = 0u;
  }
  for (int i = t; i < 4096; i += 256) lh[i] = 0u;
  __syncthreads();
  int stride = gridDim.x * blockDim.x;
  for (int j = blockIdx.x * blockDim.x + t; j < NE; j += stride)
    atomicAdd(&lh[(unsigned)(keys[j] >> 52)], 1u);
  __syncthreads();
  unsigned* gh = ghist + (size_t)blockIdx.x * 4096;
  for (int i = t; i < 4096; i += 256) gh[i] = lh[i];
}

// column-sum ghist -> hist (coalesced: consecutive threads read consecutive bins)
__global__ void k_hist_reduce(const unsigned* __restrict__ ghist, unsigned* __restrict__ hist) {
  int bin = blockIdx.x * 256 + threadIdx.x;   // 16 blocks x 256
  unsigned s = 0;
  for (int b = 0; b < HB; b++) s += ghist[(size_t)b * 4096 + bin];
  hist[bin] = s;
}

// small histogram (candidate set, sparse): LDS + atomic merge of nonzero bins
// check==0 -> NO prefix test (candidate buffer already prefix-filtered)
__global__ void k_hist(const u64* __restrict__ keys, const unsigned* __restrict__ cntp,
                       const u64* __restrict__ state,
                       unsigned* __restrict__ hist, int shift, int check) {
  __shared__ unsigned lh[4096];
  int t = threadIdx.x;
  for (int i = t; i < 4096; i += 256) lh[i] = 0u;
  __syncthreads();
  int n = (int)*cntp;
  u64 pref = state[0];
  int stride = gridDim.x * blockDim.x;
  for (int j = blockIdx.x * blockDim.x + t; j < n; j += stride) {
    u64 k = keys[j];
    bool ok = (check == 0) || (((k ^ pref) >> check) == 0ull);
    if (ok) atomicAdd(&lh[(unsigned)((k >> shift) & 4095ull)], 1u);
  }
  __syncthreads();
  for (int i = t; i < 4096; i += 256) if (lh[i]) atomicAdd(&hist[i], lh[i]);
}

// scan 4096 bins, pick bucket containing krem-th element, zero hist for reuse
__global__ void k_select(unsigned* hist, u64* state, int shift) {
  __shared__ unsigned ssum[256];
  int t = threadIdx.x;
  unsigned loc[16]; unsigned tot = 0;
  #pragma unroll
  for (int i = 0; i < 16; i++) { loc[i] = hist[t * 16 + i]; tot += loc[i]; }
  #pragma unroll
  for (int i = 0; i < 16; i++) hist[t * 16 + i] = 0u;
  unsigned krem = (unsigned)state[1];
  ssum[t] = tot; __syncthreads();
  for (int off = 1; off < 256; off <<= 1) {
    unsigned x = (t >= off) ? ssum[t - off] : 0u;
    __syncthreads();
    ssum[t] += x;
    __syncthreads();
  }
  unsigned incl = ssum[t], excl = incl - tot;
  if (incl >= krem && excl < krem) {
    unsigned run = excl; int b = 0; unsigned nk = 0;
    #pragma unroll
    for (int i = 0; i < 16; i++) {
      if (krem <= run + loc[i]) { b = t * 16 + i; nk = krem - run; break; }
      run += loc[i];
    }
    state[0] |= ((u64)b) << shift;
    state[1] = (u64)nk;
  }
}

// block-aggregated compaction: LDS staging + one global atomic per flush
__global__ void k_compact(const u64* __restrict__ keys, const unsigned* __restrict__ cntp,
                          int n_fixed, const u64* __restrict__ state, int check,
                          u64* __restrict__ outbuf, unsigned* __restrict__ cursor) {
  __shared__ u64 buf[768];
  __shared__ unsigned cnt, gbase;
  int t = threadIdx.x;
  if (t == 0) cnt = 0u;
  __syncthreads();
  int n = cntp ? (int)*cntp : n_fixed;
  u64 pref = state[0];
  int stride = gridDim.x * blockDim.x;
  for (int j0 = blockIdx.x * blockDim.x; j0 < n; j0 += stride) {
    int j = j0 + t;
    if (j < n) {
      u64 k = keys[j];
      if (((k ^ pref) >> check) == 0ull) {
        unsigned pos = atomicAdd(&cnt, 1u);
        buf[pos] = k;
      }
    }
    __syncthreads();
    if (cnt >= 512u) {
      if (t == 0) gbase = atomicAdd(cursor, cnt);
      __syncthreads();
      for (unsigned i = t; i < cnt; i += blockDim.x) outbuf[gbase + i] = buf[i];
      __syncthreads();
      if (t == 0) cnt = 0u;
      __syncthreads();
    }
  }
  if (t == 0 && cnt > 0u) gbase = atomicAdd(cursor, cnt);
  __syncthreads();
  for (unsigned i = t; i < cnt; i += blockDim.x) outbuf[gbase + i] = buf[i];
}

// finish last 40 bits on the (small) compacted candidate set, single block
__global__ void __launch_bounds__(1024) k_finish(const u64* __restrict__ cb,
                                                 const unsigned* __restrict__ cur,
                                                 u64* __restrict__ state) {
  __shared__ unsigned h[1024];
  __shared__ u64 spref;
  __shared__ unsigned skrem;
  int t = threadIdx.x;
  unsigned cnt = cur[1];
  if (t == 0) { spref = state[0]; skrem = (unsigned)state[1]; }
  __syncthreads();
  for (int shift = 30; shift >= 0; shift -= 10) {
    h[t] = 0u; __syncthreads();
    u64 pref = spref;
    for (unsigned j = t; j < cnt; j += 1024) {
      u64 k = cb[j];
      if (((k ^ pref) >> (shift + 10)) == 0ull)
        atomicAdd(&h[(unsigned)((k >> shift) & 1023ull)], 1u);
    }
    __syncthreads();
    unsigned v = h[t];
    for (int off = 1; off < 1024; off <<= 1) {
      unsigned x = (t >= off) ? h[t - off] : 0u;
      __syncthreads();
      h[t] += x;
      __syncthreads();
    }
    unsigned incl = h[t], excl = incl - v;
    unsigned krem = skrem;
    __syncthreads();
    if (incl >= krem && excl < krem) {
      spref |= ((u64)t) << shift;
      skrem = krem - excl;
    }
    __syncthreads();
  }
  if (t == 0) state[0] = spref;   // exact K-th smallest key
}

// ---------------- propagate, MLP-restructured like k_cos ----------------
// 32-lane group per node = 8 edge slots x 4 dim slices; f64 accumulate.

__global__ void k_prop(const unsigned* __restrict__ rowptr, const uint2* __restrict__ csr,
                       const u64* __restrict__ key, const u64* __restrict__ state,
                       const float* __restrict__ hn, const float* __restrict__ nrm,
                       float* __restrict__ hout) {
  int t = threadIdx.x;
  int lane = t & 31;
  int sl = lane >> 2, ds = lane & 3;
  int n = blockIdx.x * 8 + (t >> 5);
  u64 X = state[0];                         // cut iff key <= X
  unsigned j0 = rowptr[n], j1 = rowptr[n + 1];
  double acc[8];
  #pragma unroll
  for (int i = 0; i < 8; i++) acc[i] = 0.0;
  for (unsigned base = j0; base < j1; base += 8) {
    unsigned j = base + sl;
    bool val = (j < j1);
    uint2 c = val ? csr[j] : make_uint2(0u, 0u);
    u64 k = val ? key[j] : 0ull;
    bool keep = val && (k > X);
    const float4* arow = (const float4*)(hn + (size_t)c.x * DI + ds * 8);
    float4 a0 = arow[0], a1 = arow[1];      // two independent gathers
    if (keep) {
      acc[0] += (double)a0.x; acc[1] += (double)a0.y;
      acc[2] += (double)a0.z; acc[3] += (double)a0.w;
      acc[4] += (double)a1.x; acc[5] += (double)a1.y;
      acc[6] += (double)a1.z; acc[7] += (double)a1.w;
    }
  }
  #pragma unroll
  for (int m = 4; m <= 16; m <<= 1) {
    #pragma unroll
    for (int i = 0; i < 8; i++) acc[i] += __shfl_xor(acc[i], m, 32);
  }
  if (sl == 0) {                            // lanes 0..3 hold dims ds*8..ds*8+7
    float nv = nrm[n];
    float4 o0, o1;
    o0.x = (float)acc[0] * nv; o0.y = (float)acc[1] * nv;
    o0.z = (float)acc[2] * nv; o0.w = (float)acc[3] * nv;
    o1.x = (float)acc[4] * nv; o1.y = (float)acc[5] * nv;
    o1.z = (float)acc[6] * nv; o1.w = (float)acc[7] * nv;
    float4* orow = (float4*)(hout + (size_t)n * DI + ds * 8);
    orow[0] = o0; orow[1] = o1;
  }
}

// ---------------- final FC: out = h @ W^T ----------------

__global__ void k_fc(const float* __restrict__ h, const float* __restrict__ W,
                     float* __restrict__ out) {
  __shared__ float Wt[DI * 65];   // Wt[d][o], padded stride 65
  __shared__ float hs[4 * DI];
  int t = threadIdx.x;
  #pragma unroll
  for (int i = 0; i < 8; i++) {
    int idx = t + i * 256;                 // idx = o*32 + d
    Wt[(idx & 31) * 65 + (idx >> 5)] = W[idx];
  }
  int n0 = blockIdx.x * 4;
  if (t < 128) hs[t] = h[n0 * DI + t];
  __syncthreads();
  int o = t & 63, nl = t >> 6;
  float acc = 0.f;
  #pragma unroll
  for (int d = 0; d < DI; d++) acc += hs[nl * DI + d] * Wt[d * 65 + o];
  out[(n0 + nl) * DO + o] = acc;
}

// ---------------- launch ----------------

extern "C" void kernel_launch(void* const* d_in, const int* in_sizes, int n_in,
                              void* d_out, int out_size, void* d_ws, size_t ws_size,
                              hipStream_t stream) {
  const float* feat = (const float*)d_in[0];
  const int*   src  = (const int*)d_in[1];
  const int*   dst  = (const int*)d_in[2];
  const float* W    = (const float*)d_in[3];
  float*       out  = (float*)d_out;

  // workspace layout (~79 MB), all u64 pointers 8B-aligned
  float* bufA = (float*)d_ws;                       // NN*DI f32
  float* bufB = bufA + (size_t)NN * DI;
  float* bufC = bufB + (size_t)NN * DI;
  u64*   key  = (u64*)(bufC + (size_t)NN * DI);     // NE u64
  u64*   cbuf2 = key + NE;                          // NE u64 (aliased: binned, ghist)
  u64*   binned = cbuf2;                            // dead before cbuf2 is used
  unsigned* ghist = (unsigned*)cbuf2;               // HB*4096 u32 = 4MB, dead before cbuf2
  float*    nrm     = (float*)(cbuf2 + NE);
  unsigned* degi    = (unsigned*)(nrm + NN);
  unsigned* rowptr  = degi + NN;                    // NN+2 (pad keeps 8B alignment)
  unsigned* fill    = rowptr + NN + 2;              // (unused now, kept for layout stability)
  unsigned* bsum    = fill + NN;                    // 128
  unsigned* hist    = bsum + 128;                   // 4096
  unsigned* cur     = hist + 4096;                  // 2
  u64*      state   = (u64*)(cur + 2);              // 2
  uint2*    csr     = (uint2*)(state + 2);          // NE uint2
  unsigned* bhist   = (unsigned*)(csr + NE);        // 128
  unsigned* bstart  = bhist + 128;                  // NB+1 (pad to 100)
  unsigned* bcur    = bstart + 100;                 // 128

  // ---- binned CSR build (edges are hop-invariant) ----
  k_zero_u32<<<1, 128, 0, stream>>>(bhist, 128);
  k_bhist<<<512, 256, 0, stream>>>(dst, bhist);
  k_bscan<<<1, 1, 0, stream>>>(bhist, bstart, bcur);
  k_bin<<<(NE + CH - 1) / CH, 256, 0, stream>>>(src, dst, bcur, binned);
  k_bucket_deg<<<NB, 256, 0, stream>>>(binned, bstart, degi);
  k_norm<<<(NN + 255) / 256, 256, 0, stream>>>(degi, nrm);
  int nb = (NN + 1023) / 1024;   // 98
  k_psum_a<<<nb, 1024, 0, stream>>>(degi, bsum);
  k_psum_b<<<1, 1, 0, stream>>>(bsum, nb, rowptr);
  k_psum_c<<<nb, 1024, 0, stream>>>(degi, bsum, rowptr);
  size_t scatter_lds = 1024 * sizeof(unsigned) + (size_t)SCAP * sizeof(u64);  // ~156KB
  k_bucket_scatter<<<NB, 256, scatter_lds, stream>>>(binned, bstart, rowptr, csr);

  // hop 0: nh=A, hn=B, out=A, cbuf1=C   |   hop 1: nh=C, hn=B, out=C, cbuf1=A
  const float* hin = feat;
  for (int hop = 0; hop < 2; hop++) {
    float* nh = (hop == 0) ? bufA : bufC;
    float* hn = bufB;
    float* ho = (hop == 0) ? bufA : bufC;
    u64* cbuf1 = (u64*)((hop == 0) ? bufC : bufA);  // free this hop

    k_rownorm<<<NN / 8, 256, 0, stream>>>(hin, nrm, nh, hn);
    k_cos<<<NN / 8, 256, 0, stream>>>(rowptr, csr, nh, key);

    k_hist_big<<<HB, 256, 0, stream>>>(key, ghist, state, cur);  // + radix init
    k_hist_reduce<<<16, 256, 0, stream>>>(ghist, hist);
    k_select<<<1, 256, 0, stream>>>(hist, state, 52);
    k_compact<<<512, 256, 0, stream>>>(key, nullptr, NE, state, 52, cbuf1, cur + 0);
    k_hist<<<64, 256, 0, stream>>>(cbuf1, cur + 0, state, hist, 40, 0);
    k_select<<<1, 256, 0, stream>>>(hist, state, 40);
    k_compact<<<64, 256, 0, stream>>>(cbuf1, cur + 0, 0, state, 40, cbuf2, cur + 1);
    k_finish<<<1, 1024, 0, stream>>>(cbuf2, cur, state);

    k_prop<<<NN / 8, 256, 0, stream>>>(rowptr, csr, key, state, hn, nrm, ho);
    hin = ho;
  }
  k_fc<<<NN / 4, 256, 0, stream>>>(hin, W, out);
}